// Round 13
// baseline (122.612 us; speedup 1.0000x reference)
//
#include <hip/hip_runtime.h>
#include <hip/hip_bf16.h>
#include <math.h>

typedef __bf16 bf16x8 __attribute__((ext_vector_type(8)));
typedef float  f32x4  __attribute__((ext_vector_type(4)));

#define BB 2
#define C1 256
#define C2 256
#define HH 64
#define WW 64
#define HW 4096
#define OCH 27
#define EPSV 1e-5f

// workspace layout (bytes)
#define WBF_OFF  0u          // 589824 bf16 (frag-ordered w_dcn)
#define WOFF_OFF 1179648u    // 73728 bf16 (frag-ordered w_off)
#define XT_OFF   1327104u    // 2*4096*256 bf16 = 4 MB (HWC)

// ---------------------------------------------------------------------------
// MERGED prep kernel (r12 structure; wprep store path vectorized to bf16x8).
//   [0,512):   x CHW fp32 -> xT HWC bf16 (LDS transpose)
//   [512,576): w_dcn -> frag-ordered wbfS (coalesced read via LDS reorder)
//   [576,612): w_off -> frag-ordered woffS
// ---------------------------------------------------------------------------
__global__ __launch_bounds__(256) void prep_kernel(
    const float* __restrict__ x, const float* __restrict__ w_dcn,
    const float* __restrict__ w_off, __bf16* __restrict__ xT,
    __bf16* __restrict__ wbfS, __bf16* __restrict__ woffS)
{
    __shared__ __bf16 tile[64][72];
    __shared__ __bf16 lw[16][584];       // stride 584 (<=2-way banks)
    const int bi = blockIdx.x, tid = threadIdx.x;

    if (bi < 512) {
        const int b = bi >> 8;
        const int ht = (bi & 255) >> 2;
        const int ct = bi & 3;
        const int hw_l = tid & 63, cg = tid >> 6;
        const float* src = x + ((size_t)(b * 256 + ct * 64 + cg * 16) << 12)
                             + ht * 64 + hw_l;
        #pragma unroll
        for (int i = 0; i < 16; i++)
            tile[hw_l][cg * 16 + i] = (__bf16)src[(size_t)i << 12];
        __syncthreads();
        const int hw_o = tid >> 2, cq = tid & 3;
        __bf16* dst = xT + ((size_t)(b * HW + ht * 64 + hw_o) << 8)
                         + ct * 64 + cq * 16;
        *(bf16x8*)dst       = *(const bf16x8*)&tile[hw_o][cq * 16];
        *(bf16x8*)(dst + 8) = *(const bf16x8*)&tile[hw_o][cq * 16 + 8];
    } else if (bi < 576) {
        const int b2 = bi - 512;
        const int nb = b2 >> 2, qtr = b2 & 3;
        #pragma unroll
        for (int ii = 0; ii < 9; ii++) {
            int m = tid + 256 * ii;          // float4 index, < 2304
            int base = m * 4;
            int o_l = base / 576;
            int f = base - o_l * 576;
            float4 v = *(const float4*)(w_dcn
                + (size_t)(nb * 16 + o_l) * 2304 + qtr * 576 + f);
            lw[o_l][f]     = (__bf16)v.x;
            lw[o_l][f + 1] = (__bf16)v.y;
            lw[o_l][f + 2] = (__bf16)v.z;
            lw[o_l][f + 3] = (__bf16)v.w;
        }
        __syncthreads();
        // write frag order: one bf16x8 store per (seg,lane) pair, coalesced
        for (int p = tid; p < 1152; p += 256) {
            int lane = p & 63, seg = p >> 6;     // seg < 18
            int tap = seg >> 1, ks = seg & 1;
            int kb = tap * 4 + qtr;
            int o_l = lane & 15, kq = (lane >> 4) & 3;
            bf16x8 v;
            #pragma unroll
            for (int j = 0; j < 8; j++)
                v[j] = lw[o_l][(ks * 32 + kq * 8 + j) * 9 + tap];
            *(bf16x8*)(wbfS
                + ((size_t)(((kb * 2 + ks) * 16 + nb) * 64 + lane)) * 8) = v;
        }
    } else {
        int t = (bi - 576) * 256 + tid;      // < 9216
        int l = t & 63;
        int nf = (t >> 6) & 1;
        int ks = (t >> 7) & 1;
        int kb = t >> 8;
        int o = nf * 16 + (l & 15);
        int kq = (l >> 4) & 3;
        bf16x8 v;
        #pragma unroll
        for (int j = 0; j < 8; j++) {
            int K = kb * 64 + ks * 32 + kq * 8 + j;
            v[j] = (o < OCH) ? (__bf16)w_off[o * 2304 + (K & 255) * 9 + (K >> 8)]
                             : (__bf16)0.f;
        }
        *(bf16x8*)(woffS + (size_t)t * 8) = v;
    }
}

// ---------------------------------------------------------------------------
// MEGA-FUSED kernel (r12 structure + software pipelining):
//   - corner gather loads double-buffered one K-chunk ahead (long-pole
//     scattered loads get a full iteration of latency cover)
//   - 9-chunk loop fully unrolled; __launch_bounds__(256,2) caps VGPR at 256
//     (we were at 84 — headroom funds the pipeline) while keeping 2 blocks/CU
// ---------------------------------------------------------------------------
union SU {
    float sD[4][16][33];     // phase -1 reduction
    float sC[2][16][260];    // main K-reduction
};

__global__ __launch_bounds__(256, 2) void fused_kernel(
    const __bf16* __restrict__ xT, const __bf16* __restrict__ wbfS,
    const __bf16* __restrict__ woffS, const float* __restrict__ b_off,
    const float* __restrict__ gamma, const float* __restrict__ beta,
    const float* __restrict__ rmean, const float* __restrict__ rvar,
    float* __restrict__ out)
{
    __shared__ SU u;
    __shared__ float  sOm[32][16];
    __shared__ int4   sO[9][16];
    __shared__ float4 sW[9][16];

    const int tid = threadIdx.x, wv = tid >> 6, lane = tid & 63;
    const int g = (blockIdx.x & 7) * 64 + (blockIdx.x >> 3);   // XCD swizzle
    const int pixBase = g * 16;
    const int b = pixBase >> 12;
    const int hwBase = pixBase & 4095;
    const int h = hwBase >> 6, w0 = hwBase & 63;
    const int n15 = lane & 15, q4 = lane >> 4;

    const char* xb = (const char*)xT + ((size_t)b << 12) * 512;

    // ---------------- Phase -1: offset conv for this pixel tile ----------
    {
        f32x4 acc2[2];
        #pragma unroll
        for (int j = 0; j < 2; j++) acc2[j] = (f32x4){0.f, 0.f, 0.f, 0.f};

        #pragma unroll
        for (int i = 0; i < 9; i++) {
            const int kb = wv * 9 + i;
            const int k = kb >> 2, cc = kb & 3;
            const int kh = k / 3, kw = k % 3;
            const int hh = h + kh - 1;
            const int ww = w0 + n15 + kw - 1;
            const bool valid = (hh >= 0) && (hh < HH) && (ww >= 0) && (ww < WW);
            const int hc = min(max(hh, 0), HH - 1);
            const int wc = min(max(ww, 0), WW - 1);
            const char* src = xb + (size_t)(hc * WW + wc) * 512
                                 + (cc * 64 + q4 * 8) * 2;
            bf16x8 af[2];
            af[0] = *(const bf16x8*)src;
            af[1] = *(const bf16x8*)(src + 64);
            if (!valid) {
                #pragma unroll
                for (int j = 0; j < 8; j++) {
                    af[0][j] = (__bf16)0.f; af[1][j] = (__bf16)0.f;
                }
            }
            #pragma unroll
            for (int nf = 0; nf < 2; nf++) {
                #pragma unroll
                for (int ks = 0; ks < 2; ks++) {
                    bf16x8 bfr = *(const bf16x8*)(woffS
                        + ((size_t)(((kb * 2 + ks) * 2 + nf) * 64 + lane)) * 8);
                    acc2[nf] = __builtin_amdgcn_mfma_f32_16x16x32_bf16(
                        af[ks], bfr, acc2[nf], 0, 0, 0);
                }
            }
        }
        #pragma unroll
        for (int nf = 0; nf < 2; nf++)
            #pragma unroll
            for (int r = 0; r < 4; r++)
                u.sD[wv][q4 * 4 + r][nf * 16 + n15] = acc2[nf][r];
    }
    __syncthreads();
    for (int t = tid; t < OCH * 16; t += 256) {
        int oc = t >> 4, p = t & 15;
        sOm[oc][p] = b_off[oc] + u.sD[0][p][oc] + u.sD[1][p][oc]
                               + u.sD[2][p][oc] + u.sD[3][p][oc];
    }
    __syncthreads();

    // ---------------- Phase 0: bilinear metadata from sOm ----------------
    if (tid < 144) {
        int k = tid >> 4, p = tid & 15;
        float dy = sOm[2 * k][p];
        float dx = sOm[2 * k + 1][p];
        float mm = sOm[18 + k][p];
        mm = 1.f / (1.f + __expf(-mm));
        float py = (float)(h - 1 + k / 3) + dy;
        float px = (float)(w0 + p - 1 + k % 3) + dx;
        float y0f = floorf(py), x0f = floorf(px);
        float ly = py - y0f, lx = px - x0f;
        int y0 = (int)y0f, x0 = (int)x0f;
        int yc0 = min(max(y0, 0), HH - 1),     yc1 = min(max(y0 + 1, 0), HH - 1);
        int xc0 = min(max(x0, 0), WW - 1),     xc1 = min(max(x0 + 1, 0), WW - 1);
        float vy0 = (y0 >= 0 && y0 < HH) ? 1.f : 0.f;
        float vy1 = (y0 + 1 >= 0 && y0 + 1 < HH) ? 1.f : 0.f;
        float vx0 = (x0 >= 0 && x0 < WW) ? 1.f : 0.f;
        float vx1 = (x0 + 1 >= 0 && x0 + 1 < WW) ? 1.f : 0.f;
        sO[k][p] = (int4){(yc0 * WW + xc0) * 512, (yc0 * WW + xc1) * 512,
                          (yc1 * WW + xc0) * 512, (yc1 * WW + xc1) * 512};
        sW[k][p] = (float4){(1.f - ly) * (1.f - lx) * vy0 * vx0 * mm,
                            (1.f - ly) * lx         * vy0 * vx1 * mm,
                            ly         * (1.f - lx) * vy1 * vx0 * mm,
                            ly         * lx         * vy1 * vx1 * mm};
    }
    __syncthreads();

    // ---------------- Main: pipelined barrier-free K-split GEMM -----------
    f32x4 acc[16];
    #pragma unroll
    for (int j = 0; j < 16; j++) acc[j] = (f32x4){0.f, 0.f, 0.f, 0.f};

    bf16x8 cor[2][2][4];                 // [buf][ks][corner] = 64 VGPRs
    float4 Wbuf[2];

    auto loadCor = [&](int i, int buf) {
        const int kb = wv * 9 + i;
        const int k = kb >> 2, cc = kb & 3;
        const int4 O = sO[k][n15];
        Wbuf[buf] = sW[k][n15];
        const char* base = xb + (cc * 64 + q4 * 8) * 2;
        #pragma unroll
        for (int ks = 0; ks < 2; ks++) {
            const char* bc = base + ks * 64;
            cor[buf][ks][0] = *(const bf16x8*)(bc + O.x);
            cor[buf][ks][1] = *(const bf16x8*)(bc + O.y);
            cor[buf][ks][2] = *(const bf16x8*)(bc + O.z);
            cor[buf][ks][3] = *(const bf16x8*)(bc + O.w);
        }
    };

    loadCor(0, 0);
    #pragma unroll
    for (int i = 0; i < 9; i++) {
        const int kb = wv * 9 + i;
        const int buf = i & 1;

        // prefetch next chunk's scattered corner loads (full iter to land)
        if (i < 8) loadCor(i + 1, (i + 1) & 1);

        // cvt A from resident corners
        const float4 W = Wbuf[buf];
        bf16x8 af[2];
        #pragma unroll
        for (int ks = 0; ks < 2; ks++) {
            bf16x8 a;
            #pragma unroll
            for (int j = 0; j < 8; j++) {
                float v = W.x * (float)cor[buf][ks][0][j]
                        + W.y * (float)cor[buf][ks][1][j]
                        + W.z * (float)cor[buf][ks][2][j]
                        + W.w * (float)cor[buf][ks][3][j];
                a[j] = (__bf16)v;
            }
            af[ks] = a;
        }

        #pragma unroll
        for (int half = 0; half < 2; half++) {
            bf16x8 bfr[8][2];
            #pragma unroll
            for (int nb = 0; nb < 8; nb++)
                #pragma unroll
                for (int ks = 0; ks < 2; ks++)
                    bfr[nb][ks] = *(const bf16x8*)(wbfS
                        + ((size_t)(((kb * 2 + ks) * 16 + half * 8 + nb) * 64 + lane)) * 8);
            #pragma unroll
            for (int nb = 0; nb < 8; nb++)
                #pragma unroll
                for (int ks = 0; ks < 2; ks++)
                    acc[half * 8 + nb] = __builtin_amdgcn_mfma_f32_16x16x32_bf16(
                        af[ks], bfr[nb][ks], acc[half * 8 + nb], 0, 0, 0);
        }
    }

    // ---------------- 2-stage cross-wave K-reduction ----------------------
    if (wv < 2) {
        #pragma unroll
        for (int nb = 0; nb < 16; nb++)
            #pragma unroll
            for (int r = 0; r < 4; r++)
                u.sC[wv][q4 * 4 + r][nb * 16 + n15] = acc[nb][r];
    }
    __syncthreads();
    if (wv >= 2) {
        #pragma unroll
        for (int nb = 0; nb < 16; nb++)
            #pragma unroll
            for (int r = 0; r < 4; r++)
                u.sC[wv - 2][q4 * 4 + r][nb * 16 + n15] += acc[nb][r];
    }
    __syncthreads();

    // ---------------- Epilogue: BN + SiLU ---------------------------------
    const int px = tid & 15, og = tid >> 4;
    float* ob = out + ((size_t)b * C2 << 12) + hwBase + px;
    #pragma unroll
    for (int ii = 0; ii < 16; ii++) {
        int o = og * 16 + ii;
        float s = u.sC[0][px][o] + u.sC[1][px][o];
        float inv = gamma[o] * rsqrtf(rvar[o] + EPSV);
        float sh = beta[o] - rmean[o] * inv;
        float y = s * inv + sh;
        ob[(size_t)o << 12] = y * (1.f / (1.f + __expf(-y)));
    }
}

// ---------------------------------------------------------------------------
extern "C" void kernel_launch(void* const* d_in, const int* in_sizes, int n_in,
                              void* d_out, int out_size, void* d_ws, size_t ws_size,
                              hipStream_t stream) {
    const float* x      = (const float*)d_in[0];
    const float* w_off  = (const float*)d_in[1];
    const float* b_off  = (const float*)d_in[2];
    const float* w_dcn  = (const float*)d_in[3];
    const float* gamma  = (const float*)d_in[4];
    const float* beta   = (const float*)d_in[5];
    const float* rmean  = (const float*)d_in[6];
    const float* rvar   = (const float*)d_in[7];
    float* out = (float*)d_out;

    char* ws = (char*)d_ws;
    __bf16* wbfS  = (__bf16*)(ws + WBF_OFF);
    __bf16* woffS = (__bf16*)(ws + WOFF_OFF);
    __bf16* xT    = (__bf16*)(ws + XT_OFF);

    prep_kernel<<<612, 256, 0, stream>>>(x, w_dcn, w_off, xT, wbfS, woffS);
    fused_kernel<<<512, 256, 0, stream>>>(xT, wbfS, woffS, b_off,
                                          gamma, beta, rmean, rvar, out);
}

// Round 14
// 121.962 us; speedup vs baseline: 1.0053x; 1.0053x over previous
//
#include <hip/hip_runtime.h>
#include <hip/hip_bf16.h>
#include <math.h>

typedef __bf16 bf16x8 __attribute__((ext_vector_type(8)));
typedef float  f32x4  __attribute__((ext_vector_type(4)));

#define BB 2
#define C1 256
#define C2 256
#define HH 64
#define WW 64
#define HW 4096
#define OCH 27
#define EPSV 1e-5f

// workspace layout (bytes)
#define WBF_OFF  0u          // 589824 bf16 (frag-ordered w_dcn)
#define WOFF_OFF 1179648u    // 73728 bf16 (frag-ordered w_off)
#define XT_OFF   1327104u    // 2*4096*256 bf16 = 4 MB (HWC)

// ---------------------------------------------------------------------------
// MERGED prep kernel (unchanged from r13).
// ---------------------------------------------------------------------------
__global__ __launch_bounds__(256) void prep_kernel(
    const float* __restrict__ x, const float* __restrict__ w_dcn,
    const float* __restrict__ w_off, __bf16* __restrict__ xT,
    __bf16* __restrict__ wbfS, __bf16* __restrict__ woffS)
{
    __shared__ __bf16 tile[64][72];
    __shared__ __bf16 lw[16][584];
    const int bi = blockIdx.x, tid = threadIdx.x;

    if (bi < 512) {
        const int b = bi >> 8;
        const int ht = (bi & 255) >> 2;
        const int ct = bi & 3;
        const int hw_l = tid & 63, cg = tid >> 6;
        const float* src = x + ((size_t)(b * 256 + ct * 64 + cg * 16) << 12)
                             + ht * 64 + hw_l;
        #pragma unroll
        for (int i = 0; i < 16; i++)
            tile[hw_l][cg * 16 + i] = (__bf16)src[(size_t)i << 12];
        __syncthreads();
        const int hw_o = tid >> 2, cq = tid & 3;
        __bf16* dst = xT + ((size_t)(b * HW + ht * 64 + hw_o) << 8)
                         + ct * 64 + cq * 16;
        *(bf16x8*)dst       = *(const bf16x8*)&tile[hw_o][cq * 16];
        *(bf16x8*)(dst + 8) = *(const bf16x8*)&tile[hw_o][cq * 16 + 8];
    } else if (bi < 576) {
        const int b2 = bi - 512;
        const int nb = b2 >> 2, qtr = b2 & 3;
        #pragma unroll
        for (int ii = 0; ii < 9; ii++) {
            int m = tid + 256 * ii;
            int base = m * 4;
            int o_l = base / 576;
            int f = base - o_l * 576;
            float4 v = *(const float4*)(w_dcn
                + (size_t)(nb * 16 + o_l) * 2304 + qtr * 576 + f);
            lw[o_l][f]     = (__bf16)v.x;
            lw[o_l][f + 1] = (__bf16)v.y;
            lw[o_l][f + 2] = (__bf16)v.z;
            lw[o_l][f + 3] = (__bf16)v.w;
        }
        __syncthreads();
        for (int p = tid; p < 1152; p += 256) {
            int lane = p & 63, seg = p >> 6;
            int tap = seg >> 1, ks = seg & 1;
            int kb = tap * 4 + qtr;
            int o_l = lane & 15, kq = (lane >> 4) & 3;
            bf16x8 v;
            #pragma unroll
            for (int j = 0; j < 8; j++)
                v[j] = lw[o_l][(ks * 32 + kq * 8 + j) * 9 + tap];
            *(bf16x8*)(wbfS
                + ((size_t)(((kb * 2 + ks) * 16 + nb) * 64 + lane)) * 8) = v;
        }
    } else {
        int t = (bi - 576) * 256 + tid;
        int l = t & 63;
        int nf = (t >> 6) & 1;
        int ks = (t >> 7) & 1;
        int kb = t >> 8;
        int o = nf * 16 + (l & 15);
        int kq = (l >> 4) & 3;
        bf16x8 v;
        #pragma unroll
        for (int j = 0; j < 8; j++) {
            int K = kb * 64 + ks * 32 + kq * 8 + j;
            v[j] = (o < OCH) ? (__bf16)w_off[o * 2304 + (K & 255) * 9 + (K >> 8)]
                             : (__bf16)0.f;
        }
        *(bf16x8*)(woffS + (size_t)t * 8) = v;
    }
}

// ---------------------------------------------------------------------------
// MEGA-FUSED kernel, M=32 / 8-wave edition.
// Block = 512 threads (8 waves), grid 256 (1/CU, 8 waves/CU = 2/SIMD).
// K (36 chunks) split 8 ways: waves 0-3 get 5 chunks, 4-7 get 4.
// B traffic per block covers N=256 ONCE -> total B stream halves vs M=16.
// Barrier-free main loop; 4-pass LDS reduction fused with BN+SiLU epilogue.
// ---------------------------------------------------------------------------
union SU {
    float sD[8][32][33];     // phase -1 reduction (33.8 KB)
    float sRed[8][32][68];   // main reduction, nf-quarter passes (69.6 KB)
};

__global__ __launch_bounds__(512, 2) void fused_kernel(
    const __bf16* __restrict__ xT, const __bf16* __restrict__ wbfS,
    const __bf16* __restrict__ woffS, const float* __restrict__ b_off,
    const float* __restrict__ gamma, const float* __restrict__ beta,
    const float* __restrict__ rmean, const float* __restrict__ rvar,
    float* __restrict__ out)
{
    __shared__ SU u;
    __shared__ float  sOm[32][32];       // om tile [oc][px] (4 KB)
    __shared__ int4   sO[9][32];         // corner byte offsets
    __shared__ float4 sW[9][32];         // corner weights

    const int tid = threadIdx.x, wv = tid >> 6, lane = tid & 63;
    const int g = (blockIdx.x & 7) * 32 + (blockIdx.x >> 3);   // XCD swizzle
    const int pixBase = g * 32;
    const int b = pixBase >> 12;
    const int hwBase = pixBase & 4095;
    const int h = hwBase >> 6, w0 = hwBase & 63;
    const int n15 = lane & 15, q4 = lane >> 4;

    const char* xb = (const char*)xT + ((size_t)b << 12) * 512;

    const int kbStart = (wv < 4) ? wv * 5 : 20 + (wv - 4) * 4;
    const int kbCount = (wv < 4) ? 5 : 4;

    // ---------------- Phase -1: offset conv (M=32, K-split 8) -------------
    {
        f32x4 acc2[2][2];
        #pragma unroll
        for (int i = 0; i < 2; i++)
            #pragma unroll
            for (int j = 0; j < 2; j++)
                acc2[i][j] = (f32x4){0.f, 0.f, 0.f, 0.f};

        for (int ii = 0; ii < kbCount; ii++) {
            const int kb = kbStart + ii;
            const int k = kb >> 2, cc = kb & 3;
            const int kh = k / 3, kw = k % 3;
            const int hh = h + kh - 1;
            const bool vh = (hh >= 0) && (hh < HH);
            const int hc = min(max(hh, 0), HH - 1);

            bf16x8 af[2][2];
            #pragma unroll
            for (int mf = 0; mf < 2; mf++) {
                const int ww = w0 + mf * 16 + n15 + kw - 1;
                const bool valid = vh && (ww >= 0) && (ww < WW);
                const int wc = min(max(ww, 0), WW - 1);
                const char* src = xb + (size_t)(hc * WW + wc) * 512
                                     + (cc * 64 + q4 * 8) * 2;
                af[mf][0] = *(const bf16x8*)src;
                af[mf][1] = *(const bf16x8*)(src + 64);
                if (!valid) {
                    #pragma unroll
                    for (int j = 0; j < 8; j++) {
                        af[mf][0][j] = (__bf16)0.f; af[mf][1][j] = (__bf16)0.f;
                    }
                }
            }
            #pragma unroll
            for (int nf = 0; nf < 2; nf++) {
                #pragma unroll
                for (int ks = 0; ks < 2; ks++) {
                    bf16x8 bfr = *(const bf16x8*)(woffS
                        + ((size_t)(((kb * 2 + ks) * 2 + nf) * 64 + lane)) * 8);
                    #pragma unroll
                    for (int mf = 0; mf < 2; mf++)
                        acc2[mf][nf] = __builtin_amdgcn_mfma_f32_16x16x32_bf16(
                            af[mf][ks], bfr, acc2[mf][nf], 0, 0, 0);
                }
            }
        }
        #pragma unroll
        for (int mf = 0; mf < 2; mf++)
            #pragma unroll
            for (int nf = 0; nf < 2; nf++)
                #pragma unroll
                for (int r = 0; r < 4; r++)
                    u.sD[wv][mf * 16 + q4 * 4 + r][nf * 16 + n15] = acc2[mf][nf][r];
    }
    __syncthreads();
    for (int t = tid; t < OCH * 32; t += 512) {
        int oc = t >> 5, p = t & 31;
        float s = b_off[oc];
        #pragma unroll
        for (int w = 0; w < 8; w++) s += u.sD[w][p][oc];
        sOm[oc][p] = s;
    }
    __syncthreads();

    // ---------------- Phase 0: bilinear metadata (32 px x 9 taps) ---------
    if (tid < 288) {
        int k = tid >> 5, p = tid & 31;
        float dy = sOm[2 * k][p];
        float dx = sOm[2 * k + 1][p];
        float mm = sOm[18 + k][p];
        mm = 1.f / (1.f + __expf(-mm));
        float py = (float)(h - 1 + k / 3) + dy;
        float px = (float)(w0 + p - 1 + k % 3) + dx;
        float y0f = floorf(py), x0f = floorf(px);
        float ly = py - y0f, lx = px - x0f;
        int y0 = (int)y0f, x0 = (int)x0f;
        int yc0 = min(max(y0, 0), HH - 1),     yc1 = min(max(y0 + 1, 0), HH - 1);
        int xc0 = min(max(x0, 0), WW - 1),     xc1 = min(max(x0 + 1, 0), WW - 1);
        float vy0 = (y0 >= 0 && y0 < HH) ? 1.f : 0.f;
        float vy1 = (y0 + 1 >= 0 && y0 + 1 < HH) ? 1.f : 0.f;
        float vx0 = (x0 >= 0 && x0 < WW) ? 1.f : 0.f;
        float vx1 = (x0 + 1 >= 0 && x0 + 1 < WW) ? 1.f : 0.f;
        sO[k][p] = (int4){(yc0 * WW + xc0) * 512, (yc0 * WW + xc1) * 512,
                          (yc1 * WW + xc0) * 512, (yc1 * WW + xc1) * 512};
        sW[k][p] = (float4){(1.f - ly) * (1.f - lx) * vy0 * vx0 * mm,
                            (1.f - ly) * lx         * vy0 * vx1 * mm,
                            ly         * (1.f - lx) * vy1 * vx0 * mm,
                            ly         * lx         * vy1 * vx1 * mm};
    }
    __syncthreads();

    // ---------------- Main: barrier-free K-split GEMM (M=32) --------------
    f32x4 acc[2][16];                    // 128 VGPRs
    #pragma unroll
    for (int i = 0; i < 2; i++)
        #pragma unroll
        for (int j = 0; j < 16; j++)
            acc[i][j] = (f32x4){0.f, 0.f, 0.f, 0.f};

    for (int ii = 0; ii < kbCount; ii++) {
        const int kb = kbStart + ii;
        const int k = kb >> 2, cc = kb & 3;
        const char* base = xb + (cc * 64 + q4 * 8) * 2;

        bf16x8 af[2][2];
        #pragma unroll
        for (int mf = 0; mf < 2; mf++) {
            const int4   O = sO[k][mf * 16 + n15];
            const float4 W = sW[k][mf * 16 + n15];
            #pragma unroll
            for (int ks = 0; ks < 2; ks++) {
                const char* bc = base + ks * 64;
                bf16x8 c00 = *(const bf16x8*)(bc + O.x);
                bf16x8 c01 = *(const bf16x8*)(bc + O.y);
                bf16x8 c10 = *(const bf16x8*)(bc + O.z);
                bf16x8 c11 = *(const bf16x8*)(bc + O.w);
                bf16x8 a;
                #pragma unroll
                for (int j = 0; j < 8; j++) {
                    float v = W.x * (float)c00[j] + W.y * (float)c01[j]
                            + W.z * (float)c10[j] + W.w * (float)c11[j];
                    a[j] = (__bf16)v;
                }
                af[mf][ks] = a;
            }
        }

        #pragma unroll
        for (int grp = 0; grp < 4; grp++) {
            bf16x8 bfr[4][2];
            #pragma unroll
            for (int nb = 0; nb < 4; nb++)
                #pragma unroll
                for (int ks = 0; ks < 2; ks++)
                    bfr[nb][ks] = *(const bf16x8*)(wbfS
                        + ((size_t)(((kb * 2 + ks) * 16 + grp * 4 + nb) * 64 + lane)) * 8);
            #pragma unroll
            for (int nb = 0; nb < 4; nb++)
                #pragma unroll
                for (int ks = 0; ks < 2; ks++)
                    #pragma unroll
                    for (int mf = 0; mf < 2; mf++)
                        acc[mf][grp * 4 + nb] = __builtin_amdgcn_mfma_f32_16x16x32_bf16(
                            af[mf][ks], bfr[nb][ks], acc[mf][grp * 4 + nb], 0, 0, 0);
        }
    }

    // ---------------- 4-pass reduction + fused BN/SiLU epilogue -----------
    #pragma unroll
    for (int pass = 0; pass < 4; pass++) {
        #pragma unroll
        for (int mf = 0; mf < 2; mf++)
            #pragma unroll
            for (int nb = 0; nb < 4; nb++)
                #pragma unroll
                for (int r = 0; r < 4; r++)
                    u.sRed[wv][mf * 16 + q4 * 4 + r][nb * 16 + n15]
                        = acc[mf][pass * 4 + nb][r];
        __syncthreads();
        #pragma unroll
        for (int t2 = 0; t2 < 4; t2++) {
            int t = tid + t2 * 512;          // < 2048
            int px = t & 31, col = t >> 5;   // col in [0,64)
            float s = 0.f;
            #pragma unroll
            for (int w = 0; w < 8; w++) s += u.sRed[w][px][col];
            int o = pass * 64 + col;
            float inv = gamma[o] * rsqrtf(rvar[o] + EPSV);
            float sh = beta[o] - rmean[o] * inv;
            float y = s * inv + sh;
            out[(size_t)((b * C2 + o) << 12) + hwBase + px]
                = y * (1.f / (1.f + __expf(-y)));
        }
        __syncthreads();
    }
}

// ---------------------------------------------------------------------------
extern "C" void kernel_launch(void* const* d_in, const int* in_sizes, int n_in,
                              void* d_out, int out_size, void* d_ws, size_t ws_size,
                              hipStream_t stream) {
    const float* x      = (const float*)d_in[0];
    const float* w_off  = (const float*)d_in[1];
    const float* b_off  = (const float*)d_in[2];
    const float* w_dcn  = (const float*)d_in[3];
    const float* gamma  = (const float*)d_in[4];
    const float* beta   = (const float*)d_in[5];
    const float* rmean  = (const float*)d_in[6];
    const float* rvar   = (const float*)d_in[7];
    float* out = (float*)d_out;

    char* ws = (char*)d_ws;
    __bf16* wbfS  = (__bf16*)(ws + WBF_OFF);
    __bf16* woffS = (__bf16*)(ws + WOFF_OFF);
    __bf16* xT    = (__bf16*)(ws + XT_OFF);

    prep_kernel<<<612, 256, 0, stream>>>(x, w_dcn, w_off, xT, wbfS, woffS);
    fused_kernel<<<256, 512, 0, stream>>>(xT, wbfS, woffS, b_off,
                                          gamma, beta, rmean, rvar, out);
}

// Round 15
// 121.112 us; speedup vs baseline: 1.0124x; 1.0070x over previous
//
#include <hip/hip_runtime.h>
#include <hip/hip_bf16.h>
#include <math.h>

typedef __bf16 bf16x8 __attribute__((ext_vector_type(8)));
typedef float  f32x4  __attribute__((ext_vector_type(4)));

#define BB 2
#define C1 256
#define C2 256
#define HH 64
#define WW 64
#define HW 4096
#define OCH 27
#define EPSV 1e-5f

// workspace layout (bytes)
#define WBF_OFF  0u          // 589824 bf16 (frag-ordered w_dcn)
#define WOFF_OFF 1179648u    // 73728 bf16 (frag-ordered w_off)
#define XT_OFF   1327104u    // 2*4096*256 bf16 = 4 MB (HWC)

// ---------------------------------------------------------------------------
// MERGED prep kernel (unchanged from r13).
// ---------------------------------------------------------------------------
__global__ __launch_bounds__(256) void prep_kernel(
    const float* __restrict__ x, const float* __restrict__ w_dcn,
    const float* __restrict__ w_off, __bf16* __restrict__ xT,
    __bf16* __restrict__ wbfS, __bf16* __restrict__ woffS)
{
    __shared__ __bf16 tile[64][72];
    __shared__ __bf16 lw[16][584];
    const int bi = blockIdx.x, tid = threadIdx.x;

    if (bi < 512) {
        const int b = bi >> 8;
        const int ht = (bi & 255) >> 2;
        const int ct = bi & 3;
        const int hw_l = tid & 63, cg = tid >> 6;
        const float* src = x + ((size_t)(b * 256 + ct * 64 + cg * 16) << 12)
                             + ht * 64 + hw_l;
        #pragma unroll
        for (int i = 0; i < 16; i++)
            tile[hw_l][cg * 16 + i] = (__bf16)src[(size_t)i << 12];
        __syncthreads();
        const int hw_o = tid >> 2, cq = tid & 3;
        __bf16* dst = xT + ((size_t)(b * HW + ht * 64 + hw_o) << 8)
                         + ct * 64 + cq * 16;
        *(bf16x8*)dst       = *(const bf16x8*)&tile[hw_o][cq * 16];
        *(bf16x8*)(dst + 8) = *(const bf16x8*)&tile[hw_o][cq * 16 + 8];
    } else if (bi < 576) {
        const int b2 = bi - 512;
        const int nb = b2 >> 2, qtr = b2 & 3;
        #pragma unroll
        for (int ii = 0; ii < 9; ii++) {
            int m = tid + 256 * ii;
            int base = m * 4;
            int o_l = base / 576;
            int f = base - o_l * 576;
            float4 v = *(const float4*)(w_dcn
                + (size_t)(nb * 16 + o_l) * 2304 + qtr * 576 + f);
            lw[o_l][f]     = (__bf16)v.x;
            lw[o_l][f + 1] = (__bf16)v.y;
            lw[o_l][f + 2] = (__bf16)v.z;
            lw[o_l][f + 3] = (__bf16)v.w;
        }
        __syncthreads();
        for (int p = tid; p < 1152; p += 256) {
            int lane = p & 63, seg = p >> 6;
            int tap = seg >> 1, ks = seg & 1;
            int kb = tap * 4 + qtr;
            int o_l = lane & 15, kq = (lane >> 4) & 3;
            bf16x8 v;
            #pragma unroll
            for (int j = 0; j < 8; j++)
                v[j] = lw[o_l][(ks * 32 + kq * 8 + j) * 9 + tap];
            *(bf16x8*)(wbfS
                + ((size_t)(((kb * 2 + ks) * 16 + nb) * 64 + lane)) * 8) = v;
        }
    } else {
        int t = (bi - 576) * 256 + tid;
        int l = t & 63;
        int nf = (t >> 6) & 1;
        int ks = (t >> 7) & 1;
        int kb = t >> 8;
        int o = nf * 16 + (l & 15);
        int kq = (l >> 4) & 3;
        bf16x8 v;
        #pragma unroll
        for (int j = 0; j < 8; j++) {
            int K = kb * 64 + ks * 32 + kq * 8 + j;
            v[j] = (o < OCH) ? (__bf16)w_off[o * 2304 + (K & 255) * 9 + (K >> 8)]
                             : (__bf16)0.f;
        }
        *(bf16x8*)(woffS + (size_t)t * 8) = v;
    }
}

// ---------------------------------------------------------------------------
// MEGA-FUSED kernel — r13 structure (M=16, 4 waves, grid 512, barrier-free
// K-split) with LDS cut to ~23.5 KB (2-pass K-reduction) so occupancy rises
// from 2 to ~5-6 blocks/CU (~5 waves/SIMD): pure latency-hiding play.
// No launch-bounds cap; no manual pipeline (r13 showed it neutral).
// ---------------------------------------------------------------------------
union SU {
    float sD[4][16][33];     // phase -1 reduction (8.4 KB)
    float sC[2][16][132];    // main K-reduction, half-N passes (16.9 KB)
};

__global__ __launch_bounds__(256) void fused_kernel(
    const __bf16* __restrict__ xT, const __bf16* __restrict__ wbfS,
    const __bf16* __restrict__ woffS, const float* __restrict__ b_off,
    const float* __restrict__ gamma, const float* __restrict__ beta,
    const float* __restrict__ rmean, const float* __restrict__ rvar,
    float* __restrict__ out)
{
    __shared__ SU u;
    __shared__ float  sOm[32][16];       // 2 KB
    __shared__ int4   sO[9][16];         // 2.3 KB
    __shared__ float4 sW[9][16];         // 2.3 KB

    const int tid = threadIdx.x, wv = tid >> 6, lane = tid & 63;
    const int g = (blockIdx.x & 7) * 64 + (blockIdx.x >> 3);   // XCD swizzle
    const int pixBase = g * 16;
    const int b = pixBase >> 12;
    const int hwBase = pixBase & 4095;
    const int h = hwBase >> 6, w0 = hwBase & 63;
    const int n15 = lane & 15, q4 = lane >> 4;

    const char* xb = (const char*)xT + ((size_t)b << 12) * 512;

    // ---------------- Phase -1: offset conv for this pixel tile ----------
    {
        f32x4 acc2[2];
        #pragma unroll
        for (int j = 0; j < 2; j++) acc2[j] = (f32x4){0.f, 0.f, 0.f, 0.f};

        #pragma unroll
        for (int i = 0; i < 9; i++) {
            const int kb = wv * 9 + i;
            const int k = kb >> 2, cc = kb & 3;
            const int kh = k / 3, kw = k % 3;
            const int hh = h + kh - 1;
            const int ww = w0 + n15 + kw - 1;
            const bool valid = (hh >= 0) && (hh < HH) && (ww >= 0) && (ww < WW);
            const int hc = min(max(hh, 0), HH - 1);
            const int wc = min(max(ww, 0), WW - 1);
            const char* src = xb + (size_t)(hc * WW + wc) * 512
                                 + (cc * 64 + q4 * 8) * 2;
            bf16x8 af[2];
            af[0] = *(const bf16x8*)src;
            af[1] = *(const bf16x8*)(src + 64);
            if (!valid) {
                #pragma unroll
                for (int j = 0; j < 8; j++) {
                    af[0][j] = (__bf16)0.f; af[1][j] = (__bf16)0.f;
                }
            }
            #pragma unroll
            for (int nf = 0; nf < 2; nf++) {
                #pragma unroll
                for (int ks = 0; ks < 2; ks++) {
                    bf16x8 bfr = *(const bf16x8*)(woffS
                        + ((size_t)(((kb * 2 + ks) * 2 + nf) * 64 + lane)) * 8);
                    acc2[nf] = __builtin_amdgcn_mfma_f32_16x16x32_bf16(
                        af[ks], bfr, acc2[nf], 0, 0, 0);
                }
            }
        }
        #pragma unroll
        for (int nf = 0; nf < 2; nf++)
            #pragma unroll
            for (int r = 0; r < 4; r++)
                u.sD[wv][q4 * 4 + r][nf * 16 + n15] = acc2[nf][r];
    }
    __syncthreads();
    for (int t = tid; t < OCH * 16; t += 256) {
        int oc = t >> 4, p = t & 15;
        sOm[oc][p] = b_off[oc] + u.sD[0][p][oc] + u.sD[1][p][oc]
                               + u.sD[2][p][oc] + u.sD[3][p][oc];
    }
    __syncthreads();

    // ---------------- Phase 0: bilinear metadata from sOm ----------------
    if (tid < 144) {
        int k = tid >> 4, p = tid & 15;
        float dy = sOm[2 * k][p];
        float dx = sOm[2 * k + 1][p];
        float mm = sOm[18 + k][p];
        mm = 1.f / (1.f + __expf(-mm));
        float py = (float)(h - 1 + k / 3) + dy;
        float px = (float)(w0 + p - 1 + k % 3) + dx;
        float y0f = floorf(py), x0f = floorf(px);
        float ly = py - y0f, lx = px - x0f;
        int y0 = (int)y0f, x0 = (int)x0f;
        int yc0 = min(max(y0, 0), HH - 1),     yc1 = min(max(y0 + 1, 0), HH - 1);
        int xc0 = min(max(x0, 0), WW - 1),     xc1 = min(max(x0 + 1, 0), WW - 1);
        float vy0 = (y0 >= 0 && y0 < HH) ? 1.f : 0.f;
        float vy1 = (y0 + 1 >= 0 && y0 + 1 < HH) ? 1.f : 0.f;
        float vx0 = (x0 >= 0 && x0 < WW) ? 1.f : 0.f;
        float vx1 = (x0 + 1 >= 0 && x0 + 1 < WW) ? 1.f : 0.f;
        sO[k][p] = (int4){(yc0 * WW + xc0) * 512, (yc0 * WW + xc1) * 512,
                          (yc1 * WW + xc0) * 512, (yc1 * WW + xc1) * 512};
        sW[k][p] = (float4){(1.f - ly) * (1.f - lx) * vy0 * vx0 * mm,
                            (1.f - ly) * lx         * vy0 * vx1 * mm,
                            ly         * (1.f - lx) * vy1 * vx0 * mm,
                            ly         * lx         * vy1 * vx1 * mm};
    }
    __syncthreads();

    // ---------------- Main: barrier-free K-split GEMM ---------------------
    f32x4 acc[16];                       // 64 VGPRs
    #pragma unroll
    for (int j = 0; j < 16; j++) acc[j] = (f32x4){0.f, 0.f, 0.f, 0.f};

    for (int i = 0; i < 9; i++) {
        const int kb = wv * 9 + i;
        const int k = kb >> 2, cc = kb & 3;
        const int4   O = sO[k][n15];
        const float4 W = sW[k][n15];
        const char* base = xb + (cc * 64 + q4 * 8) * 2;

        bf16x8 af[2];
        #pragma unroll
        for (int ks = 0; ks < 2; ks++) {
            const char* bc = base + ks * 64;
            bf16x8 c00 = *(const bf16x8*)(bc + O.x);
            bf16x8 c01 = *(const bf16x8*)(bc + O.y);
            bf16x8 c10 = *(const bf16x8*)(bc + O.z);
            bf16x8 c11 = *(const bf16x8*)(bc + O.w);
            bf16x8 a;
            #pragma unroll
            for (int j = 0; j < 8; j++) {
                float v = W.x * (float)c00[j] + W.y * (float)c01[j]
                        + W.z * (float)c10[j] + W.w * (float)c11[j];
                a[j] = (__bf16)v;
            }
            af[ks] = a;
        }

        #pragma unroll
        for (int half = 0; half < 2; half++) {
            bf16x8 bfr[8][2];
            #pragma unroll
            for (int nb = 0; nb < 8; nb++)
                #pragma unroll
                for (int ks = 0; ks < 2; ks++)
                    bfr[nb][ks] = *(const bf16x8*)(wbfS
                        + ((size_t)(((kb * 2 + ks) * 16 + half * 8 + nb) * 64 + lane)) * 8);
            #pragma unroll
            for (int nb = 0; nb < 8; nb++)
                #pragma unroll
                for (int ks = 0; ks < 2; ks++)
                    acc[half * 8 + nb] = __builtin_amdgcn_mfma_f32_16x16x32_bf16(
                        af[ks], bfr[nb][ks], acc[half * 8 + nb], 0, 0, 0);
        }
    }

    // ------- 2-pass cross-wave K-reduction + fused BN/SiLU epilogue -------
    #pragma unroll
    for (int pass = 0; pass < 2; pass++) {
        if (wv < 2) {
            #pragma unroll
            for (int nb = 0; nb < 8; nb++)
                #pragma unroll
                for (int r = 0; r < 4; r++)
                    u.sC[wv][q4 * 4 + r][nb * 16 + n15] = acc[pass * 8 + nb][r];
        }
        __syncthreads();
        if (wv >= 2) {
            #pragma unroll
            for (int nb = 0; nb < 8; nb++)
                #pragma unroll
                for (int r = 0; r < 4; r++)
                    u.sC[wv - 2][q4 * 4 + r][nb * 16 + n15] += acc[pass * 8 + nb][r];
        }
        __syncthreads();

        const int px = tid & 15, og = tid >> 4;   // og in [0,16)
        #pragma unroll
        for (int ii = 0; ii < 8; ii++) {
            int col = og * 8 + ii;               // [0,128)
            int o = pass * 128 + col;
            float s = u.sC[0][px][col] + u.sC[1][px][col];
            float inv = gamma[o] * rsqrtf(rvar[o] + EPSV);
            float sh = beta[o] - rmean[o] * inv;
            float y = s * inv + sh;
            out[(size_t)((b * C2 + o) << 12) + hwBase + px]
                = y * (1.f / (1.f + __expf(-y)));
        }
        __syncthreads();
    }
}

// ---------------------------------------------------------------------------
extern "C" void kernel_launch(void* const* d_in, const int* in_sizes, int n_in,
                              void* d_out, int out_size, void* d_ws, size_t ws_size,
                              hipStream_t stream) {
    const float* x      = (const float*)d_in[0];
    const float* w_off  = (const float*)d_in[1];
    const float* b_off  = (const float*)d_in[2];
    const float* w_dcn  = (const float*)d_in[3];
    const float* gamma  = (const float*)d_in[4];
    const float* beta   = (const float*)d_in[5];
    const float* rmean  = (const float*)d_in[6];
    const float* rvar   = (const float*)d_in[7];
    float* out = (float*)d_out;

    char* ws = (char*)d_ws;
    __bf16* wbfS  = (__bf16*)(ws + WBF_OFF);
    __bf16* woffS = (__bf16*)(ws + WOFF_OFF);
    __bf16* xT    = (__bf16*)(ws + XT_OFF);

    prep_kernel<<<612, 256, 0, stream>>>(x, w_dcn, w_off, xT, wbfS, woffS);
    fused_kernel<<<512, 256, 0, stream>>>(xT, wbfS, woffS, b_off,
                                          gamma, beta, rmean, rvar, out);
}